// Round 12
// baseline (367.672 us; speedup 1.0000x reference)
//
#include <hip/hip_runtime.h>
#include <math.h>

#define EPS_LN 1e-6f
#define EPS_BN 1e-5f

typedef __attribute__((ext_vector_type(8))) short bf16x8;
typedef __attribute__((ext_vector_type(4))) float f32x4;

__device__ __forceinline__ float wave_reduce_sum(float v) {
    #pragma unroll
    for (int m = 32; m >= 1; m >>= 1) v += __shfl_xor(v, m, 64);
    return v;
}
__device__ __forceinline__ float wave_reduce_max(float v) {
    #pragma unroll
    for (int m = 32; m >= 1; m >>= 1) v = fmaxf(v, __shfl_xor(v, m, 64));
    return v;
}
__device__ __forceinline__ short f2bf(float f) {
    union { float f; unsigned u; } v; v.f = f;
    unsigned r = v.u + 0x7fff + ((v.u >> 16) & 1);
    return (short)(r >> 16);
}
__device__ __forceinline__ unsigned pack2bf(float a, float b) {
    return (unsigned)(unsigned short)f2bf(a) | ((unsigned)(unsigned short)f2bf(b) << 16);
}
// tanh-approx gelu (sigmoid form); ~8 VALU ops
__device__ __forceinline__ float gelu_f(float x) {
    float x2 = x * x;
    float u = x * (-1.595769122f - 0.071354816f * x2);
    float e = __expf(u);
    return x * __builtin_amdgcn_rcpf(1.f + e);
}

// ---------------- patch embed: dw3x3 s2 + pw 64->128 + BN(d) + hardswish ----
__global__ __launch_bounds__(256) void pe_kernel(
    const float* __restrict__ img, const float* __restrict__ dww,
    const float* __restrict__ pww, const float* __restrict__ bn_g,
    const float* __restrict__ bn_b, const float* __restrict__ bn_m,
    const float* __restrict__ bn_v, const int* __restrict__ dptr,
    float* __restrict__ t1) {
    __shared__ float dw[64 * 68];
    __shared__ float wsm[64 * 132];
    int bx = blockIdx.x;
    int b = bx >> 6, y = bx & 63;
    int tid = threadIdx.x;
    int d = *dptr;

    for (int idx = tid; idx < 8192; idx += 256) {
        int co = idx >> 6, ci = idx & 63;
        wsm[ci * 132 + co] = pww[idx];
    }

    for (int it = 0; it < 4; ++it) {
        int task = tid + it * 256;
        int ci = task >> 4, xx0 = (task & 15) * 4;
        const float* ip = img + (size_t)(b * 64 + ci) * 16384;
        const float* wd = dww + ci * 9;
        float a0 = 0.f, a1 = 0.f, a2 = 0.f, a3 = 0.f;
        #pragma unroll
        for (int r = 0; r < 3; ++r) {
            int iy = 2 * y + r;
            if (iy >= 128) continue;
            const float* rp = ip + iy * 128 + 2 * xx0;
            float u[9];
            *(f32x4*)&u[0] = *(const f32x4*)rp;
            *(f32x4*)&u[4] = *(const f32x4*)(rp + 4);
            u[8] = (xx0 < 60) ? rp[8] : 0.f;
            #pragma unroll
            for (int s = 0; s < 3; ++s) {
                float w = wd[r * 3 + s];
                a0 += u[s] * w;
                a1 += u[2 + s] * w;
                a2 += u[4 + s] * w;
                a3 += u[6 + s] * w;
            }
        }
        f32x4 st = {a0, a1, a2, a3};
        *(f32x4*)&dw[ci * 68 + xx0] = st;
    }
    __syncthreads();

    int xg = tid & 15, cog = tid >> 4;
    int xx0 = xg * 4, co0 = cog * 8;
    f32x4 acc[8];
    f32x4 zr = {0.f, 0.f, 0.f, 0.f};
    #pragma unroll
    for (int i = 0; i < 8; ++i) acc[i] = zr;
    for (int ci = 0; ci < 64; ++ci) {
        f32x4 dv = *(const f32x4*)&dw[ci * 68 + xx0];
        f32x4 w0 = *(const f32x4*)&wsm[ci * 132 + co0];
        f32x4 w1 = *(const f32x4*)&wsm[ci * 132 + co0 + 4];
        acc[0] += dv * w0.x; acc[1] += dv * w0.y;
        acc[2] += dv * w0.z; acc[3] += dv * w0.w;
        acc[4] += dv * w1.x; acc[5] += dv * w1.y;
        acc[6] += dv * w1.z; acc[7] += dv * w1.w;
    }
    #pragma unroll
    for (int i = 0; i < 8; ++i) {
        int co = co0 + i;
        float sc = bn_g[d * 128 + co] * rsqrtf(bn_v[d * 128 + co] + EPS_BN);
        float mu = bn_m[d * 128 + co], be = bn_b[d * 128 + co];
        f32x4 v = (acc[i] - mu) * sc + be;
        f32x4 r;
        r.x = v.x * fminf(fmaxf(v.x + 3.f, 0.f), 6.f) * (1.f / 6.f);
        r.y = v.y * fminf(fmaxf(v.y + 3.f, 0.f), 6.f) * (1.f / 6.f);
        r.z = v.z * fminf(fmaxf(v.z + 3.f, 0.f), 6.f) * (1.f / 6.f);
        r.w = v.w * fminf(fmaxf(v.w + 3.f, 0.f), 6.f) * (1.f / 6.f);
        *(f32x4*)&t1[(size_t)(b * 128 + co) * 4096 + y * 64 + xx0] = r;
    }
}

// ---------------- ConvPosEnc ----------------
__global__ __launch_bounds__(256) void cpe_kernel(
    const float* __restrict__ t1, const float* __restrict__ cw,
    const float* __restrict__ cb, float* __restrict__ xout) {
    int bx = blockIdx.x;
    int cq = bx & 3, y = (bx >> 2) & 63, b = bx >> 8;
    int c0 = cq * 32;
    __shared__ float s[3 * 32 * 65];
    int tid = threadIdx.x;
    for (int idx = tid; idx < 3 * 32 * 64; idx += 256) {
        int xx = idx & 63;
        int cl = (idx >> 6) & 31;
        int dy = idx >> 11;
        int yy = y + dy - 1;
        float v = 0.f;
        if (yy >= 0 && yy < 64)
            v = t1[(size_t)(b * 128 + c0 + cl) * 4096 + yy * 64 + xx];
        s[(dy * 32 + cl) * 65 + xx] = v;
    }
    __syncthreads();
    for (int idx = tid; idx < 32 * 64; idx += 256) {
        int cl = idx & 31;
        int xx = idx >> 5;
        int c = c0 + cl;
        float center = s[(32 + cl) * 65 + xx];
        float acc = cb[c];
        #pragma unroll
        for (int dy = 0; dy < 3; ++dy) {
            #pragma unroll
            for (int dx = 0; dx < 3; ++dx) {
                int sx = xx + dx - 1;
                if (sx < 0 || sx >= 64) continue;
                acc += s[(dy * 32 + cl) * 65 + sx] * cw[c * 9 + dy * 3 + dx];
            }
        }
        xout[(size_t)(b * 4096 + y * 64 + xx) * 128 + c] = center + acc;
    }
}

// ---------------- fused prep: all weight packs + bias folds + gate ---------
__global__ __launch_bounds__(256) void prep_kernel(
    const float* __restrict__ qkv_w, const float* __restrict__ n1_g,
    const float* __restrict__ n1_b, const float* __restrict__ qkv_b,
    const float* __restrict__ pw, const float* __restrict__ f1w,
    const float* __restrict__ n2_g, const float* __restrict__ n2_b,
    const float* __restrict__ f1b, const float* __restrict__ f2w,
    const float* __restrict__ dl, const float* __restrict__ dw1,
    const float* __restrict__ db1, const float* __restrict__ dw2,
    const float* __restrict__ db2, const int* __restrict__ dptr,
    short* __restrict__ qkvp, short* __restrict__ pwp,
    short* __restrict__ w1p, short* __restrict__ w2p,
    float* __restrict__ qbp, float* __restrict__ f1bp,
    float* __restrict__ da) {
    __shared__ float sh[1536];
    int bb = blockIdx.x;
    int tid = threadIdx.x;
    int d = *dptr;
    if (bb < 24) {
        int idx = bb * 256 + tid;
        int l = idx & 63, kk = (idx >> 6) & 3, n = idx >> 8;
        int k0 = kk * 32 + (l >> 4) * 8;
        int c = n * 16 + (l & 15);
        bf16x8 v;
        #pragma unroll
        for (int j = 0; j < 8; ++j)
            v[j] = f2bf(n1_g[d * 128 + k0 + j] * qkv_w[(size_t)(k0 + j) * 384 + c]);
        *(bf16x8*)&qkvp[(size_t)idx * 8] = v;
    } else if (bb < 32) {
        int idx = (bb - 24) * 256 + tid;
        int l = idx & 63, kk = (idx >> 6) & 3, n = idx >> 8;
        int k0 = kk * 32 + (l >> 4) * 8;
        int c = n * 16 + (l & 15);
        bf16x8 v;
        #pragma unroll
        for (int j = 0; j < 8; ++j) v[j] = f2bf(pw[(size_t)(k0 + j) * 128 + c]);
        *(bf16x8*)&pwp[(size_t)idx * 8] = v;
    } else if (bb < 96) {
        int idx = (bb - 32) * 256 + tid;
        int l = idx & 63, kk = (idx >> 6) & 3, n = idx >> 8;
        int k0 = kk * 32 + (l >> 4) * 8;
        int c = n * 16 + (l & 15);
        bf16x8 v;
        #pragma unroll
        for (int j = 0; j < 8; ++j)
            v[j] = f2bf(n2_g[d * 128 + k0 + j] * f1w[(size_t)(k0 + j) * 1024 + c]);
        *(bf16x8*)&w1p[(size_t)idx * 8] = v;
    } else if (bb < 160) {
        int idx = (bb - 96) * 256 + tid;
        int l = idx & 63, kk = (idx >> 6) & 31, n = idx >> 11;
        int k0 = kk * 32 + (l >> 4) * 8;
        int c = n * 16 + (l & 15);
        bf16x8 v;
        #pragma unroll
        for (int j = 0; j < 8; ++j) v[j] = f2bf(f2w[(size_t)(k0 + j) * 128 + c]);
        *(bf16x8*)&w2p[(size_t)idx * 8] = v;
    } else if (bb < 162) {
        int j = (bb - 160) * 256 + tid;
        if (j < 384) {
            float s = qkv_b[j];
            for (int k = 0; k < 128; ++k)
                s += n1_b[d * 128 + k] * qkv_w[(size_t)k * 384 + j];
            qbp[j] = s;
        }
    } else if (bb < 166) {
        int j = (bb - 162) * 256 + tid;
        float s = f1b[j];
        for (int k = 0; k < 128; ++k)
            s += n2_b[d * 128 + k] * f1w[(size_t)k * 1024 + j];
        f1bp[j] = s;
    } else {
        float* hid = sh;
        float* raw = sh + 512;
        for (int idx = tid; idx < 512; idx += 256) {
            int b = idx >> 6, jj = idx & 63;
            float a = db1[jj];
            #pragma unroll
            for (int dd = 0; dd < 4; ++dd)
                a += dl[b * 4 + dd] * dw1[dd * 64 + jj];
            hid[idx] = fmaxf(a, 0.f);
        }
        __syncthreads();
        for (int idx = tid; idx < 1024; idx += 256) {
            int b = idx >> 7, c = idx & 127;
            float a = db2[c];
            for (int jj = 0; jj < 64; ++jj)
                a += hid[b * 64 + jj] * dw2[jj * 128 + c];
            raw[idx] = a;
        }
        __syncthreads();
        if (tid < 128) {
            int b = tid >> 4, ch = tid & 15;
            float mx = -1e30f;
            #pragma unroll
            for (int hh = 0; hh < 8; ++hh)
                mx = fmaxf(mx, raw[b * 128 + hh * 16 + ch]);
            float e[8];
            float s = 0.f;
            #pragma unroll
            for (int hh = 0; hh < 8; ++hh) {
                e[hh] = expf(raw[b * 128 + hh * 16 + ch] - mx);
                s += e[hh];
            }
            float inv = 1.f / s;
            #pragma unroll
            for (int hh = 0; hh < 8; ++hh)
                da[b * 128 + hh * 16 + ch] = e[hh] * inv;
        }
    }
}

// ---------------- MFMA QKV (LN1 fused): 512 thr, 8 waves, wave-split tt ----
__global__ __launch_bounds__(512, 4) void qkv_mfma_kernel(
    const float* __restrict__ x, const short* __restrict__ wp,
    const float* __restrict__ biasp, float* __restrict__ q_img,
    float* __restrict__ k_img, float* __restrict__ v_img) {
    int tb = blockIdx.x * 32;
    int tid = threadIdx.x;
    int lane = tid & 63, wv = tid >> 6;
    int tt = wv & 1, g = wv >> 1;
    int lhi = lane >> 4, llo = lane & 15;
    int b = tb >> 12, n0 = tb & 4095;

    bf16x8 afr[4];
    {
        f32x4 v0[4], v1[4];
        float sum = 0.f;
        #pragma unroll
        for (int kk = 0; kk < 4; ++kk) {
            const float* p = x + (size_t)(tb + tt * 16 + llo) * 128 + kk * 32 + lhi * 8;
            v0[kk] = *(const f32x4*)p;
            v1[kk] = *(const f32x4*)(p + 4);
            sum += v0[kk].x + v0[kk].y + v0[kk].z + v0[kk].w
                 + v1[kk].x + v1[kk].y + v1[kk].z + v1[kk].w;
        }
        sum += __shfl_xor(sum, 16, 64);
        sum += __shfl_xor(sum, 32, 64);
        float mean = sum * (1.f / 128.f);
        float vs = 0.f;
        #pragma unroll
        for (int kk = 0; kk < 4; ++kk) {
            f32x4 a = v0[kk], c = v1[kk];
            float d0 = a.x - mean, d1 = a.y - mean, d2 = a.z - mean, d3 = a.w - mean;
            float d4 = c.x - mean, d5 = c.y - mean, d6 = c.z - mean, d7 = c.w - mean;
            vs += d0*d0 + d1*d1 + d2*d2 + d3*d3 + d4*d4 + d5*d5 + d6*d6 + d7*d7;
        }
        vs += __shfl_xor(vs, 16, 64);
        vs += __shfl_xor(vs, 32, 64);
        float rs = rsqrtf(vs * (1.f / 128.f) + EPS_LN);
        #pragma unroll
        for (int kk = 0; kk < 4; ++kk) {
            bf16x8 o;
            o[0] = f2bf((v0[kk].x - mean) * rs);
            o[1] = f2bf((v0[kk].y - mean) * rs);
            o[2] = f2bf((v0[kk].z - mean) * rs);
            o[3] = f2bf((v0[kk].w - mean) * rs);
            o[4] = f2bf((v1[kk].x - mean) * rs);
            o[5] = f2bf((v1[kk].y - mean) * rs);
            o[6] = f2bf((v1[kk].z - mean) * rs);
            o[7] = f2bf((v1[kk].w - mean) * rs);
            afr[kk] = o;
        }
    }

    f32x4 acc[6];
    f32x4 zr = {0.f, 0.f, 0.f, 0.f};
    #pragma unroll
    for (int i = 0; i < 6; ++i) acc[i] = zr;

    #pragma unroll
    for (int i = 0; i < 6; ++i) {
        int nb = g * 6 + i;
        #pragma unroll
        for (int kk = 0; kk < 4; ++kk) {
            bf16x8 wf = *(const bf16x8*)&wp[((size_t)(nb * 4 + kk) * 64 + lane) * 8];
            acc[i] = __builtin_amdgcn_mfma_f32_16x16x32_bf16(wf, afr[kk], acc[i], 0, 0, 0);
        }
    }

    #pragma unroll
    for (int i = 0; i < 6; ++i) {
        int j0 = (g * 6 + i) * 16;
        f32x4 bv = *(const f32x4*)(biasp + j0 + lhi * 4);
        float* dst = (j0 < 128) ? q_img : ((j0 < 256) ? k_img : v_img);
        int c0 = (j0 & 127) + lhi * 4;
        f32x4 r = acc[i] + bv;
        float* p = dst + (size_t)(b * 128 + c0) * 4096 + n0 + tt * 16 + llo;
        p[0]        = r.x;
        p[4096]     = r.y;
        p[2 * 4096] = r.z;
        p[3 * 4096] = r.w;
    }
}

// ---------------- softmax over N ---------------
__global__ __launch_bounds__(256) void softmax_kernel(float* __restrict__ k_img) {
    __shared__ float red[4];
    float* p = k_img + (size_t)blockIdx.x * 4096;
    int tid = threadIdx.x;
    float v[16];
    float mx = -1e30f;
    #pragma unroll
    for (int i = 0; i < 16; ++i) {
        v[i] = p[tid + i * 256];
        mx = fmaxf(mx, v[i]);
    }
    mx = wave_reduce_max(mx);
    int wid = tid >> 6, lane = tid & 63;
    if (lane == 0) red[wid] = mx;
    __syncthreads();
    mx = fmaxf(fmaxf(red[0], red[1]), fmaxf(red[2], red[3]));
    __syncthreads();
    float sum = 0.f;
    #pragma unroll
    for (int i = 0; i < 16; ++i) {
        v[i] = expf(v[i] - mx);
        sum += v[i];
    }
    sum = wave_reduce_sum(sum);
    if (lane == 0) red[wid] = sum;
    __syncthreads();
    float inv = 1.f / (red[0] + red[1] + red[2] + red[3]);
    #pragma unroll
    for (int i = 0; i < 16; ++i)
        p[tid + i * 256] = v[i] * inv;
}

// ---------------- kv partial: grid 512 = bh*8+chunk, n-chunk of 512 --------
__global__ __launch_bounds__(256) void kv_part_kernel(
    const float* __restrict__ k_img, const float* __restrict__ v_img,
    float* __restrict__ kvp) {
    __shared__ float ks[16 * 132], vs[16 * 132];
    int bc = blockIdx.x;
    int bh = bc >> 3, chunk = bc & 7;
    int b = bh >> 3, h = bh & 7;
    int tid = threadIdx.x;
    int ck = tid >> 4, cv = tid & 15;
    float acc = 0.f;
    const float* kp = k_img + (size_t)(b * 128 + h * 16) * 4096;
    const float* vp = v_img + (size_t)(b * 128 + h * 16) * 4096;
    int nb0 = chunk * 512;
    for (int nb = nb0; nb < nb0 + 512; nb += 128) {
        for (int idx = tid; idx < 2048; idx += 256) {
            int r = idx >> 7, col = idx & 127;
            ks[r * 132 + col] = kp[(size_t)r * 4096 + nb + col];
            vs[r * 132 + col] = vp[(size_t)r * 4096 + nb + col];
        }
        __syncthreads();
        for (int kk = 0; kk < 128; ++kk)
            acc += ks[ck * 132 + kk] * vs[cv * 132 + kk];
        __syncthreads();
    }
    kvp[(size_t)(chunk * 64 + bh) * 256 + ck * 16 + cv] = acc;
}

// ---------------- fa (with inline kvp reduce) ------------------------------
__global__ __launch_bounds__(256) void fa_kernel(
    const float* __restrict__ q_img, const float* __restrict__ kvp,
    float* __restrict__ fa_img) {
    __shared__ float kvs[256];
    int bid = blockIdx.x;
    int bh = bid >> 4, chunk = bid & 15;
    int b = bh >> 3, h = bh & 7;
    int tid = threadIdx.x;
    {
        float s = 0.f;
        #pragma unroll
        for (int c = 0; c < 8; ++c) s += kvp[(size_t)c * 16384 + bh * 256 + tid];
        kvs[tid] = s;
    }
    __syncthreads();
    int n = chunk * 256 + tid;
    const float* qp = q_img + (size_t)(b * 128 + h * 16) * 4096 + n;
    float qv[16];
    #pragma unroll
    for (int ck = 0; ck < 16; ++ck) qv[ck] = qp[(size_t)ck * 4096];
    float* fp = fa_img + (size_t)(b * 128 + h * 16) * 4096 + n;
    #pragma unroll
    for (int cv = 0; cv < 16; ++cv) {
        float s = 0.f;
        #pragma unroll
        for (int ck = 0; ck < 16; ++ck) s += qv[ck] * kvs[ck * 16 + cv];
        fp[(size_t)cv * 4096] = s;
    }
}

// ---------------- conv helper: 4 outputs, compile-time KC (rule #20) -------
template<int KC>
__device__ __forceinline__ void conv4(const float* __restrict__ s,
                                      const float* __restrict__ wsm,
                                      int y, int xx0, float* a4) {
    const int OFF = KC / 2;
    #pragma unroll
    for (int dy = 0; dy < KC; ++dy) {
        int sy = y + dy - OFF;
        if (sy < 0 || sy >= 64) continue;
        const float* r = s + sy * 72;
        float u[12];
        *(f32x4*)&u[0] = *(const f32x4*)&r[xx0];
        *(f32x4*)&u[4] = *(const f32x4*)&r[xx0 + 4];
        *(f32x4*)&u[8] = *(const f32x4*)&r[xx0 + 8];
        #pragma unroll
        for (int dx = 0; dx < KC; ++dx) {
            float w = wsm[dy * KC + dx];
            const int base = dx - OFF + 4;
            a4[0] += u[base + 0] * w;
            a4[1] += u[base + 1] * w;
            a4[2] += u[base + 2] * w;
            a4[3] += u[base + 3] * w;
        }
    }
}

// ---------------- crpe conv + combine (fa precomputed) ---------------------
__global__ __launch_bounds__(256) void att_kernel(
    const float* __restrict__ q_img, const float* __restrict__ v_img,
    const float* __restrict__ fa_img, const float* __restrict__ da,
    const float* __restrict__ w3, const float* __restrict__ b3,
    const float* __restrict__ w5, const float* __restrict__ b5,
    const float* __restrict__ w7, const float* __restrict__ b7,
    float* __restrict__ att) {
    __shared__ float s[64 * 72];
    __shared__ float wsm[49];
    int o = ((blockIdx.x & 7) << 7) | (blockIdx.x >> 3);
    int b = o >> 7, c = o & 127;
    int tid = threadIdx.x;
    const float* vp = v_img + (size_t)(b * 128 + c) * 4096;
    for (int idx = tid; idx < 4096; idx += 256) {
        int row = idx >> 6, xx = idx & 63;
        s[row * 72 + xx + 4] = vp[idx];
    }
    for (int idx = tid; idx < 512; idx += 256) {
        int row = idx >> 3, j = idx & 7;
        s[row * 72 + (j < 4 ? j : 64 + j)] = 0.f;
    }
    int kc; const float* wp; float bias;
    if (c < 32)      { kc = 3; wp = w3 + c * 9;         bias = b3[c]; }
    else if (c < 80) { kc = 5; wp = w5 + (c - 32) * 25; bias = b5[c - 32]; }
    else             { kc = 7; wp = w7 + (c - 80) * 49; bias = b7[c - 80]; }
    if (tid < kc * kc) wsm[tid] = wp[tid];
    float dac = da[b * 128 + c];
    size_t rowbase = (size_t)(b * 128 + c) * 4096;
    __syncthreads();
    for (int it = 0; it < 4; ++it) {
        int task = tid + it * 256;
        int y = task >> 4, xx0 = (task & 15) * 4;
        float a4[4] = {bias, bias, bias, bias};
        if (kc == 3)      conv4<3>(s, wsm, y, xx0, a4);
        else if (kc == 5) conv4<5>(s, wsm, y, xx0, a4);
        else              conv4<7>(s, wsm, y, xx0, a4);
        size_t base = rowbase + y * 64 + xx0;
        f32x4 fav = *(const f32x4*)&fa_img[base];
        f32x4 qv  = *(const f32x4*)&q_img[base];
        f32x4 cv4 = {a4[0], a4[1], a4[2], a4[3]};
        f32x4 r = (fav * 0.25f + qv * cv4) * dac;
        *(f32x4*)&att[base] = r;
    }
}

// ---------------- MFMA proj + residual: A = att (image layout) -------------
__global__ __launch_bounds__(256, 2) void proj_mfma_kernel(
    const float* __restrict__ att, const short* __restrict__ wp,
    const float* __restrict__ bias, const float* __restrict__ xres,
    float* __restrict__ out) {
    __shared__ float As[128 * 33];
    int tb = blockIdx.x * 32;
    int tid = threadIdx.x;
    int lane = tid & 63, wv = tid >> 6;
    int lhi = lane >> 4, llo = lane & 15;
    int b = tb >> 12, n0 = tb & 4095;

    for (int idx = tid; idx < 4096; idx += 256) {
        int c = idx >> 5, t = idx & 31;
        As[c * 33 + t] = att[(size_t)(b * 128 + c) * 4096 + n0 + t];
    }
    __syncthreads();

    bf16x8 afr[2][4];
    #pragma unroll
    for (int tt = 0; tt < 2; ++tt) {
        #pragma unroll
        for (int kk = 0; kk < 4; ++kk) {
            int c0 = kk * 32 + lhi * 8;
            int t = tt * 16 + llo;
            bf16x8 v;
            #pragma unroll
            for (int j = 0; j < 8; ++j) v[j] = f2bf(As[(c0 + j) * 33 + t]);
            afr[tt][kk] = v;
        }
    }

    f32x4 acc[2][2];
    f32x4 zr = {0.f, 0.f, 0.f, 0.f};
    #pragma unroll
    for (int i = 0; i < 2; ++i) { acc[i][0] = zr; acc[i][1] = zr; }

    #pragma unroll
    for (int i = 0; i < 2; ++i) {
        int nb = wv * 2 + i;
        #pragma unroll
        for (int kk = 0; kk < 4; ++kk) {
            bf16x8 wf = *(const bf16x8*)&wp[((size_t)(nb * 4 + kk) * 64 + lane) * 8];
            acc[i][0] = __builtin_amdgcn_mfma_f32_16x16x32_bf16(wf, afr[0][kk], acc[i][0], 0, 0, 0);
            acc[i][1] = __builtin_amdgcn_mfma_f32_16x16x32_bf16(wf, afr[1][kk], acc[i][1], 0, 0, 0);
        }
    }

    #pragma unroll
    for (int i = 0; i < 2; ++i) {
        int j0 = (wv * 2 + i) * 16;
        f32x4 bv = *(const f32x4*)(bias + j0 + lhi * 4);
        #pragma unroll
        for (int tt = 0; tt < 2; ++tt) {
            size_t o = (size_t)(tb + tt * 16 + llo) * 128 + j0 + lhi * 4;
            f32x4 xr = *(const f32x4*)(xres + o);
            *(f32x4*)(out + o) = xr + acc[i][tt] + bv;
        }
    }
}

// ---------------- fused MFMA MLP (LN2 fused), 2 K-phases, 40KB LDS ---------
// LN computed once (waves 0/1), afr broadcast via LDS (identical across waves).
// Phase p: GEMM1 computes hn = p*32 + wv*4 + nl (nl<4, both tt) -> hs (16 kk2
// slots, 32KB); GEMM2 accumulates kk2 = p*16..p*16+15 into acc2 across phases.
// All acc arrays statically indexed (rule #20).
__global__ __launch_bounds__(512, 6) void mlp_mfma_kernel(
    const short* __restrict__ w1p, const float* __restrict__ b1p,
    const short* __restrict__ w2p, const float* __restrict__ b2,
    float* io) {
    __shared__ short afs[2 * 4 * 64 * 8];    // 8KB: LN'd a-frags
    __shared__ short hs[2 * 16 * 64 * 8];    // 32KB: one K-phase of hid
    int tb = blockIdx.x * 32;
    int tid = threadIdx.x;
    int lane = tid & 63, wv = tid >> 6;
    int lhi = lane >> 4, llo = lane & 15;

    if (wv < 2) {
        int tt = wv;
        f32x4 v0[4], v1[4];
        float sum = 0.f;
        #pragma unroll
        for (int kk = 0; kk < 4; ++kk) {
            const float* p = io + (size_t)(tb + tt * 16 + llo) * 128 + kk * 32 + lhi * 8;
            v0[kk] = *(const f32x4*)p;
            v1[kk] = *(const f32x4*)(p + 4);
            sum += v0[kk].x + v0[kk].y + v0[kk].z + v0[kk].w
                 + v1[kk].x + v1[kk].y + v1[kk].z + v1[kk].w;
        }
        sum += __shfl_xor(sum, 16, 64);
        sum += __shfl_xor(sum, 32, 64);
        float mean = sum * (1.f / 128.f);
        float vs = 0.f;
        #pragma unroll
        for (int kk = 0; kk < 4; ++kk) {
            f32x4 a = v0[kk], c = v1[kk];
            float d0 = a.x - mean, d1 = a.y - mean, d2 = a.z - mean, d3 = a.w - mean;
            float d4 = c.x - mean, d5 = c.y - mean, d6 = c.z - mean, d7 = c.w - mean;
            vs += d0*d0 + d1*d1 + d2*d2 + d3*d3 + d4*d4 + d5*d5 + d6*d6 + d7*d7;
        }
        vs += __shfl_xor(vs, 16, 64);
        vs += __shfl_xor(vs, 32, 64);
        float rs = rsqrtf(vs * (1.f / 128.f) + EPS_LN);
        #pragma unroll
        for (int kk = 0; kk < 4; ++kk) {
            bf16x8 o;
            o[0] = f2bf((v0[kk].x - mean) * rs);
            o[1] = f2bf((v0[kk].y - mean) * rs);
            o[2] = f2bf((v0[kk].z - mean) * rs);
            o[3] = f2bf((v0[kk].w - mean) * rs);
            o[4] = f2bf((v1[kk].x - mean) * rs);
            o[5] = f2bf((v1[kk].y - mean) * rs);
            o[6] = f2bf((v1[kk].z - mean) * rs);
            o[7] = f2bf((v1[kk].w - mean) * rs);
            *(bf16x8*)&afs[((size_t)(tt * 4 + kk) * 64 + lane) * 8] = o;
        }
    }
    __syncthreads();

    bf16x8 afr[2][4];
    #pragma unroll
    for (int tt = 0; tt < 2; ++tt)
        #pragma unroll
        for (int kk = 0; kk < 4; ++kk)
            afr[tt][kk] = *(const bf16x8*)&afs[((size_t)(tt * 4 + kk) * 64 + lane) * 8];

    f32x4 zr = {0.f, 0.f, 0.f, 0.f};
    f32x4 acc2[2];
    acc2[0] = zr; acc2[1] = zr;

    #pragma unroll
    for (int p = 0; p < 2; ++p) {
        f32x4 acc[2][4];
        #pragma unroll
        for (int tt = 0; tt < 2; ++tt)
            #pragma unroll
            for (int nl = 0; nl < 4; ++nl) acc[tt][nl] = zr;

        const short* wbase = w1p + (size_t)(p * 32 + wv * 4) * 4 * 64 * 8;
        #pragma unroll
        for (int nl = 0; nl < 4; ++nl) {
            #pragma unroll
            for (int kk = 0; kk < 4; ++kk) {
                bf16x8 bf = *(const bf16x8*)(wbase + ((size_t)(nl * 4 + kk) * 64 + lane) * 8);
                acc[0][nl] = __builtin_amdgcn_mfma_f32_16x16x32_bf16(bf, afr[0][kk], acc[0][nl], 0, 0, 0);
                acc[1][nl] = __builtin_amdgcn_mfma_f32_16x16x32_bf16(bf, afr[1][kk], acc[1][nl], 0, 0, 0);
            }
        }

        #pragma unroll
        for (int nl = 0; nl < 4; ++nl) {
            int hn = p * 32 + wv * 4 + nl;
            int kk2l = wv * 2 + (nl >> 1);
            int hc0 = hn * 16 + lhi * 4;
            f32x4 bv = *(const f32x4*)(b1p + hc0);
            int lp = llo + 16 * ((hn & 1) * 2 + (lhi >> 1));
            #pragma unroll
            for (int tt = 0; tt < 2; ++tt) {
                f32x4 a = acc[tt][nl] + bv;
                uint2 wv2;
                wv2.x = pack2bf(gelu_f(a.x), gelu_f(a.y));
                wv2.y = pack2bf(gelu_f(a.z), gelu_f(a.w));
                *(uint2*)((char*)hs + ((size_t)(tt * 16 + kk2l) * 64 + lp) * 16 + (lhi & 1) * 8) = wv2;
            }
        }
        __syncthreads();   // hs ready for this phase

        const short* w2base = w2p + (size_t)(wv * 32 + p * 16) * 64 * 8;
        #pragma unroll 4
        for (int kk2l = 0; kk2l < 16; ++kk2l) {
            bf16x8 h0 = *(const bf16x8*)&hs[((size_t)(0 * 16 + kk2l) * 64 + lane) * 8];
            bf16x8 h1 = *(const bf16x8*)&hs[((size_t)(1 * 16 + kk2l) * 64 + lane) * 8];
            bf16x8 w0 = *(const bf16x8*)(w2base + ((size_t)kk2l * 64 + lane) * 8);
            acc2[0] = __builtin_amdgcn_mfma_f32_16x16x32_bf16(w0, h0, acc2[0], 0, 0, 0);
            acc2[1] = __builtin_amdgcn_mfma_f32_16x16x32_bf16(w0, h1, acc2[1], 0, 0, 0);
        }
        if (p == 0) __syncthreads();   // drain reads before phase-1 overwrite
    }

    int c0 = wv * 16 + lhi * 4;
    f32x4 bv = *(const f32x4*)(b2 + c0);
    #pragma unroll
    for (int tt2 = 0; tt2 < 2; ++tt2) {
        float* op = io + (size_t)(tb + tt2 * 16 + llo) * 128 + c0;
        f32x4 r = *(f32x4*)op;
        r = r + acc2[tt2] + bv;
        *(f32x4*)op = r;
    }
}

extern "C" void kernel_launch(void* const* d_in, const int* in_sizes, int n_in,
                              void* d_out, int out_size, void* d_ws, size_t ws_size,
                              hipStream_t stream) {
    const float* img   = (const float*)d_in[0];
    const float* dl    = (const float*)d_in[1];
    const float* pe_dw = (const float*)d_in[2];
    const float* pe_pw = (const float*)d_in[3];
    const float* bn_g  = (const float*)d_in[4];
    const float* bn_b  = (const float*)d_in[5];
    const float* bn_m  = (const float*)d_in[6];
    const float* bn_v  = (const float*)d_in[7];
    const float* cpe_w = (const float*)d_in[8];
    const float* cpe_b = (const float*)d_in[9];
    const float* n1_g  = (const float*)d_in[10];
    const float* n1_b  = (const float*)d_in[11];
    const float* qkv_w = (const float*)d_in[12];
    const float* qkv_b = (const float*)d_in[13];
    const float* w3    = (const float*)d_in[14];
    const float* b3    = (const float*)d_in[15];
    const float* w5    = (const float*)d_in[16];
    const float* b5    = (const float*)d_in[17];
    const float* w7    = (const float*)d_in[18];
    const float* b7    = (const float*)d_in[19];
    const float* dw1   = (const float*)d_in[20];
    const float* db1   = (const float*)d_in[21];
    const float* dw2   = (const float*)d_in[22];
    const float* db2   = (const float*)d_in[23];
    const float* pw    = (const float*)d_in[24];
    const float* pb    = (const float*)d_in[25];
    const float* n2_g  = (const float*)d_in[26];
    const float* n2_b  = (const float*)d_in[27];
    const float* f1w   = (const float*)d_in[28];
    const float* f1b   = (const float*)d_in[29];
    const float* f2w   = (const float*)d_in[30];
    const float* f2b   = (const float*)d_in[31];
    const int*   dptr  = (const int*)d_in[32];
    float* out = (float*)d_out;

    char* ws = (char*)d_ws;
    const size_t SZ = (size_t)8 * 128 * 4096 * 4;   // 16,777,216 bytes
    float* t1    = (float*)(ws);            // pe out; dead after cpe -> fa_img
    float* x     = (float*)(ws + SZ);       // residual stream after cpe
    float* q_img = (float*)(ws + 2 * SZ);
    float* k_img = (float*)(ws + 3 * SZ);   // att output after kv
    float* v_img = (float*)(ws + 4 * SZ);
    float* da    = (float*)(ws + 5 * SZ + 0x10000);
    short* qkvp  = (short*)(ws + 5 * SZ + 0x20000);
    short* pwp   = (short*)(ws + 5 * SZ + 0x40000);
    float* qbp   = (float*)(ws + 5 * SZ + 0x48000);
    float* f1bp  = (float*)(ws + 5 * SZ + 0x4A000);
    float* kvp   = (float*)(ws + 5 * SZ + 0x50000);
    short* w1p   = (short*)(ws + 5 * SZ + 0xD0000);
    short* w2p   = (short*)(ws + 5 * SZ + 0x110000);
    float* fa_img = t1;

    prep_kernel<<<167, 256, 0, stream>>>(qkv_w, n1_g, n1_b, qkv_b, pw, f1w,
                                         n2_g, n2_b, f1b, f2w, dl, dw1, db1,
                                         dw2, db2, dptr, qkvp, pwp, w1p, w2p,
                                         qbp, f1bp, da);
    pe_kernel<<<512, 256, 0, stream>>>(img, pe_dw, pe_pw, bn_g, bn_b, bn_m, bn_v, dptr, t1);
    cpe_kernel<<<2048, 256, 0, stream>>>(t1, cpe_w, cpe_b, x);
    qkv_mfma_kernel<<<1024, 512, 0, stream>>>(x, qkvp, qbp, q_img, k_img, v_img);
    softmax_kernel<<<1024, 256, 0, stream>>>(k_img);
    kv_part_kernel<<<512, 256, 0, stream>>>(k_img, v_img, kvp);
    fa_kernel<<<1024, 256, 0, stream>>>(q_img, kvp, fa_img);
    att_kernel<<<1024, 256, 0, stream>>>(q_img, v_img, fa_img, da, w3, b3, w5, b5, w7, b7, k_img);
    proj_mfma_kernel<<<1024, 256, 0, stream>>>(k_img, pwp, pb, x, out);
    mlp_mfma_kernel<<<1024, 512, 0, stream>>>(w1p, f1bp, w2p, f2b, out);
}

// Round 13
// 332.017 us; speedup vs baseline: 1.1074x; 1.1074x over previous
//
#include <hip/hip_runtime.h>
#include <math.h>

#define EPS_LN 1e-6f
#define EPS_BN 1e-5f

typedef __attribute__((ext_vector_type(8))) short bf16x8;
typedef __attribute__((ext_vector_type(4))) float f32x4;

__device__ __forceinline__ float wave_reduce_sum(float v) {
    #pragma unroll
    for (int m = 32; m >= 1; m >>= 1) v += __shfl_xor(v, m, 64);
    return v;
}
__device__ __forceinline__ float wave_reduce_max(float v) {
    #pragma unroll
    for (int m = 32; m >= 1; m >>= 1) v = fmaxf(v, __shfl_xor(v, m, 64));
    return v;
}
__device__ __forceinline__ short f2bf(float f) {
    union { float f; unsigned u; } v; v.f = f;
    unsigned r = v.u + 0x7fff + ((v.u >> 16) & 1);
    return (short)(r >> 16);
}
__device__ __forceinline__ unsigned pack2bf(float a, float b) {
    return (unsigned)(unsigned short)f2bf(a) | ((unsigned)(unsigned short)f2bf(b) << 16);
}
// tanh-approx gelu (sigmoid form); ~8 VALU ops
__device__ __forceinline__ float gelu_f(float x) {
    float x2 = x * x;
    float u = x * (-1.595769122f - 0.071354816f * x2);
    float e = __expf(u);
    return x * __builtin_amdgcn_rcpf(1.f + e);
}

// ---------------- patch embed: dw3x3 s2 + pw 64->128 + BN(d) + hardswish ----
__global__ __launch_bounds__(256) void pe_kernel(
    const float* __restrict__ img, const float* __restrict__ dww,
    const float* __restrict__ pww, const float* __restrict__ bn_g,
    const float* __restrict__ bn_b, const float* __restrict__ bn_m,
    const float* __restrict__ bn_v, const int* __restrict__ dptr,
    float* __restrict__ t1) {
    __shared__ float dw[64 * 68];
    __shared__ float wsm[64 * 132];
    int bx = blockIdx.x;
    int b = bx >> 6, y = bx & 63;
    int tid = threadIdx.x;
    int d = *dptr;

    for (int idx = tid; idx < 8192; idx += 256) {
        int co = idx >> 6, ci = idx & 63;
        wsm[ci * 132 + co] = pww[idx];
    }

    for (int it = 0; it < 4; ++it) {
        int task = tid + it * 256;
        int ci = task >> 4, xx0 = (task & 15) * 4;
        const float* ip = img + (size_t)(b * 64 + ci) * 16384;
        const float* wd = dww + ci * 9;
        float a0 = 0.f, a1 = 0.f, a2 = 0.f, a3 = 0.f;
        #pragma unroll
        for (int r = 0; r < 3; ++r) {
            int iy = 2 * y + r;
            if (iy >= 128) continue;
            const float* rp = ip + iy * 128 + 2 * xx0;
            float u[9];
            *(f32x4*)&u[0] = *(const f32x4*)rp;
            *(f32x4*)&u[4] = *(const f32x4*)(rp + 4);
            u[8] = (xx0 < 60) ? rp[8] : 0.f;
            #pragma unroll
            for (int s = 0; s < 3; ++s) {
                float w = wd[r * 3 + s];
                a0 += u[s] * w;
                a1 += u[2 + s] * w;
                a2 += u[4 + s] * w;
                a3 += u[6 + s] * w;
            }
        }
        f32x4 st = {a0, a1, a2, a3};
        *(f32x4*)&dw[ci * 68 + xx0] = st;
    }
    __syncthreads();

    int xg = tid & 15, cog = tid >> 4;
    int xx0 = xg * 4, co0 = cog * 8;
    f32x4 acc[8];
    f32x4 zr = {0.f, 0.f, 0.f, 0.f};
    #pragma unroll
    for (int i = 0; i < 8; ++i) acc[i] = zr;
    for (int ci = 0; ci < 64; ++ci) {
        f32x4 dv = *(const f32x4*)&dw[ci * 68 + xx0];
        f32x4 w0 = *(const f32x4*)&wsm[ci * 132 + co0];
        f32x4 w1 = *(const f32x4*)&wsm[ci * 132 + co0 + 4];
        acc[0] += dv * w0.x; acc[1] += dv * w0.y;
        acc[2] += dv * w0.z; acc[3] += dv * w0.w;
        acc[4] += dv * w1.x; acc[5] += dv * w1.y;
        acc[6] += dv * w1.z; acc[7] += dv * w1.w;
    }
    #pragma unroll
    for (int i = 0; i < 8; ++i) {
        int co = co0 + i;
        float sc = bn_g[d * 128 + co] * rsqrtf(bn_v[d * 128 + co] + EPS_BN);
        float mu = bn_m[d * 128 + co], be = bn_b[d * 128 + co];
        f32x4 v = (acc[i] - mu) * sc + be;
        f32x4 r;
        r.x = v.x * fminf(fmaxf(v.x + 3.f, 0.f), 6.f) * (1.f / 6.f);
        r.y = v.y * fminf(fmaxf(v.y + 3.f, 0.f), 6.f) * (1.f / 6.f);
        r.z = v.z * fminf(fmaxf(v.z + 3.f, 0.f), 6.f) * (1.f / 6.f);
        r.w = v.w * fminf(fmaxf(v.w + 3.f, 0.f), 6.f) * (1.f / 6.f);
        *(f32x4*)&t1[(size_t)(b * 128 + co) * 4096 + y * 64 + xx0] = r;
    }
}

// ---------------- ConvPosEnc ----------------
__global__ __launch_bounds__(256) void cpe_kernel(
    const float* __restrict__ t1, const float* __restrict__ cw,
    const float* __restrict__ cb, float* __restrict__ xout) {
    int bx = blockIdx.x;
    int cq = bx & 3, y = (bx >> 2) & 63, b = bx >> 8;
    int c0 = cq * 32;
    __shared__ float s[3 * 32 * 65];
    int tid = threadIdx.x;
    for (int idx = tid; idx < 3 * 32 * 64; idx += 256) {
        int xx = idx & 63;
        int cl = (idx >> 6) & 31;
        int dy = idx >> 11;
        int yy = y + dy - 1;
        float v = 0.f;
        if (yy >= 0 && yy < 64)
            v = t1[(size_t)(b * 128 + c0 + cl) * 4096 + yy * 64 + xx];
        s[(dy * 32 + cl) * 65 + xx] = v;
    }
    __syncthreads();
    for (int idx = tid; idx < 32 * 64; idx += 256) {
        int cl = idx & 31;
        int xx = idx >> 5;
        int c = c0 + cl;
        float center = s[(32 + cl) * 65 + xx];
        float acc = cb[c];
        #pragma unroll
        for (int dy = 0; dy < 3; ++dy) {
            #pragma unroll
            for (int dx = 0; dx < 3; ++dx) {
                int sx = xx + dx - 1;
                if (sx < 0 || sx >= 64) continue;
                acc += s[(dy * 32 + cl) * 65 + sx] * cw[c * 9 + dy * 3 + dx];
            }
        }
        xout[(size_t)(b * 4096 + y * 64 + xx) * 128 + c] = center + acc;
    }
}

// ---------------- fused prep: all weight packs + bias folds + gate ---------
__global__ __launch_bounds__(256) void prep_kernel(
    const float* __restrict__ qkv_w, const float* __restrict__ n1_g,
    const float* __restrict__ n1_b, const float* __restrict__ qkv_b,
    const float* __restrict__ pw, const float* __restrict__ f1w,
    const float* __restrict__ n2_g, const float* __restrict__ n2_b,
    const float* __restrict__ f1b, const float* __restrict__ f2w,
    const float* __restrict__ dl, const float* __restrict__ dw1,
    const float* __restrict__ db1, const float* __restrict__ dw2,
    const float* __restrict__ db2, const int* __restrict__ dptr,
    short* __restrict__ qkvp, short* __restrict__ pwp,
    short* __restrict__ w1p, short* __restrict__ w2p,
    float* __restrict__ qbp, float* __restrict__ f1bp,
    float* __restrict__ da) {
    __shared__ float sh[1536];
    int bb = blockIdx.x;
    int tid = threadIdx.x;
    int d = *dptr;
    if (bb < 24) {
        int idx = bb * 256 + tid;
        int l = idx & 63, kk = (idx >> 6) & 3, n = idx >> 8;
        int k0 = kk * 32 + (l >> 4) * 8;
        int c = n * 16 + (l & 15);
        bf16x8 v;
        #pragma unroll
        for (int j = 0; j < 8; ++j)
            v[j] = f2bf(n1_g[d * 128 + k0 + j] * qkv_w[(size_t)(k0 + j) * 384 + c]);
        *(bf16x8*)&qkvp[(size_t)idx * 8] = v;
    } else if (bb < 32) {
        int idx = (bb - 24) * 256 + tid;
        int l = idx & 63, kk = (idx >> 6) & 3, n = idx >> 8;
        int k0 = kk * 32 + (l >> 4) * 8;
        int c = n * 16 + (l & 15);
        bf16x8 v;
        #pragma unroll
        for (int j = 0; j < 8; ++j) v[j] = f2bf(pw[(size_t)(k0 + j) * 128 + c]);
        *(bf16x8*)&pwp[(size_t)idx * 8] = v;
    } else if (bb < 96) {
        int idx = (bb - 32) * 256 + tid;
        int l = idx & 63, kk = (idx >> 6) & 3, n = idx >> 8;
        int k0 = kk * 32 + (l >> 4) * 8;
        int c = n * 16 + (l & 15);
        bf16x8 v;
        #pragma unroll
        for (int j = 0; j < 8; ++j)
            v[j] = f2bf(n2_g[d * 128 + k0 + j] * f1w[(size_t)(k0 + j) * 1024 + c]);
        *(bf16x8*)&w1p[(size_t)idx * 8] = v;
    } else if (bb < 160) {
        int idx = (bb - 96) * 256 + tid;
        int l = idx & 63, kk = (idx >> 6) & 31, n = idx >> 11;
        int k0 = kk * 32 + (l >> 4) * 8;
        int c = n * 16 + (l & 15);
        bf16x8 v;
        #pragma unroll
        for (int j = 0; j < 8; ++j) v[j] = f2bf(f2w[(size_t)(k0 + j) * 128 + c]);
        *(bf16x8*)&w2p[(size_t)idx * 8] = v;
    } else if (bb < 162) {
        int j = (bb - 160) * 256 + tid;
        if (j < 384) {
            float s = qkv_b[j];
            for (int k = 0; k < 128; ++k)
                s += n1_b[d * 128 + k] * qkv_w[(size_t)k * 384 + j];
            qbp[j] = s;
        }
    } else if (bb < 166) {
        int j = (bb - 162) * 256 + tid;
        float s = f1b[j];
        for (int k = 0; k < 128; ++k)
            s += n2_b[d * 128 + k] * f1w[(size_t)k * 1024 + j];
        f1bp[j] = s;
    } else {
        float* hid = sh;
        float* raw = sh + 512;
        for (int idx = tid; idx < 512; idx += 256) {
            int b = idx >> 6, jj = idx & 63;
            float a = db1[jj];
            #pragma unroll
            for (int dd = 0; dd < 4; ++dd)
                a += dl[b * 4 + dd] * dw1[dd * 64 + jj];
            hid[idx] = fmaxf(a, 0.f);
        }
        __syncthreads();
        for (int idx = tid; idx < 1024; idx += 256) {
            int b = idx >> 7, c = idx & 127;
            float a = db2[c];
            for (int jj = 0; jj < 64; ++jj)
                a += hid[b * 64 + jj] * dw2[jj * 128 + c];
            raw[idx] = a;
        }
        __syncthreads();
        if (tid < 128) {
            int b = tid >> 4, ch = tid & 15;
            float mx = -1e30f;
            #pragma unroll
            for (int hh = 0; hh < 8; ++hh)
                mx = fmaxf(mx, raw[b * 128 + hh * 16 + ch]);
            float e[8];
            float s = 0.f;
            #pragma unroll
            for (int hh = 0; hh < 8; ++hh) {
                e[hh] = expf(raw[b * 128 + hh * 16 + ch] - mx);
                s += e[hh];
            }
            float inv = 1.f / s;
            #pragma unroll
            for (int hh = 0; hh < 8; ++hh)
                da[b * 128 + hh * 16 + ch] = e[hh] * inv;
        }
    }
}

// ---------------- MFMA QKV (LN1 fused): 512 thr, 8 waves, wave-split tt ----
__global__ __launch_bounds__(512, 4) void qkv_mfma_kernel(
    const float* __restrict__ x, const short* __restrict__ wp,
    const float* __restrict__ biasp, float* __restrict__ q_img,
    float* __restrict__ k_img, float* __restrict__ v_img) {
    int tb = blockIdx.x * 32;
    int tid = threadIdx.x;
    int lane = tid & 63, wv = tid >> 6;
    int tt = wv & 1, g = wv >> 1;
    int lhi = lane >> 4, llo = lane & 15;
    int b = tb >> 12, n0 = tb & 4095;

    bf16x8 afr[4];
    {
        f32x4 v0[4], v1[4];
        float sum = 0.f;
        #pragma unroll
        for (int kk = 0; kk < 4; ++kk) {
            const float* p = x + (size_t)(tb + tt * 16 + llo) * 128 + kk * 32 + lhi * 8;
            v0[kk] = *(const f32x4*)p;
            v1[kk] = *(const f32x4*)(p + 4);
            sum += v0[kk].x + v0[kk].y + v0[kk].z + v0[kk].w
                 + v1[kk].x + v1[kk].y + v1[kk].z + v1[kk].w;
        }
        sum += __shfl_xor(sum, 16, 64);
        sum += __shfl_xor(sum, 32, 64);
        float mean = sum * (1.f / 128.f);
        float vs = 0.f;
        #pragma unroll
        for (int kk = 0; kk < 4; ++kk) {
            f32x4 a = v0[kk], c = v1[kk];
            float d0 = a.x - mean, d1 = a.y - mean, d2 = a.z - mean, d3 = a.w - mean;
            float d4 = c.x - mean, d5 = c.y - mean, d6 = c.z - mean, d7 = c.w - mean;
            vs += d0*d0 + d1*d1 + d2*d2 + d3*d3 + d4*d4 + d5*d5 + d6*d6 + d7*d7;
        }
        vs += __shfl_xor(vs, 16, 64);
        vs += __shfl_xor(vs, 32, 64);
        float rs = rsqrtf(vs * (1.f / 128.f) + EPS_LN);
        #pragma unroll
        for (int kk = 0; kk < 4; ++kk) {
            bf16x8 o;
            o[0] = f2bf((v0[kk].x - mean) * rs);
            o[1] = f2bf((v0[kk].y - mean) * rs);
            o[2] = f2bf((v0[kk].z - mean) * rs);
            o[3] = f2bf((v0[kk].w - mean) * rs);
            o[4] = f2bf((v1[kk].x - mean) * rs);
            o[5] = f2bf((v1[kk].y - mean) * rs);
            o[6] = f2bf((v1[kk].z - mean) * rs);
            o[7] = f2bf((v1[kk].w - mean) * rs);
            afr[kk] = o;
        }
    }

    f32x4 acc[6];
    f32x4 zr = {0.f, 0.f, 0.f, 0.f};
    #pragma unroll
    for (int i = 0; i < 6; ++i) acc[i] = zr;

    #pragma unroll
    for (int i = 0; i < 6; ++i) {
        int nb = g * 6 + i;
        #pragma unroll
        for (int kk = 0; kk < 4; ++kk) {
            bf16x8 wf = *(const bf16x8*)&wp[((size_t)(nb * 4 + kk) * 64 + lane) * 8];
            acc[i] = __builtin_amdgcn_mfma_f32_16x16x32_bf16(wf, afr[kk], acc[i], 0, 0, 0);
        }
    }

    #pragma unroll
    for (int i = 0; i < 6; ++i) {
        int j0 = (g * 6 + i) * 16;
        f32x4 bv = *(const f32x4*)(biasp + j0 + lhi * 4);
        float* dst = (j0 < 128) ? q_img : ((j0 < 256) ? k_img : v_img);
        int c0 = (j0 & 127) + lhi * 4;
        f32x4 r = acc[i] + bv;
        float* p = dst + (size_t)(b * 128 + c0) * 4096 + n0 + tt * 16 + llo;
        p[0]        = r.x;
        p[4096]     = r.y;
        p[2 * 4096] = r.z;
        p[3 * 4096] = r.w;
    }
}

// ---------------- softmax over N ---------------
__global__ __launch_bounds__(256) void softmax_kernel(float* __restrict__ k_img) {
    __shared__ float red[4];
    float* p = k_img + (size_t)blockIdx.x * 4096;
    int tid = threadIdx.x;
    float v[16];
    float mx = -1e30f;
    #pragma unroll
    for (int i = 0; i < 16; ++i) {
        v[i] = p[tid + i * 256];
        mx = fmaxf(mx, v[i]);
    }
    mx = wave_reduce_max(mx);
    int wid = tid >> 6, lane = tid & 63;
    if (lane == 0) red[wid] = mx;
    __syncthreads();
    mx = fmaxf(fmaxf(red[0], red[1]), fmaxf(red[2], red[3]));
    __syncthreads();
    float sum = 0.f;
    #pragma unroll
    for (int i = 0; i < 16; ++i) {
        v[i] = expf(v[i] - mx);
        sum += v[i];
    }
    sum = wave_reduce_sum(sum);
    if (lane == 0) red[wid] = sum;
    __syncthreads();
    float inv = 1.f / (red[0] + red[1] + red[2] + red[3]);
    #pragma unroll
    for (int i = 0; i < 16; ++i)
        p[tid + i * 256] = v[i] * inv;
}

// ---------------- kv partial: grid 512 = bh*8+chunk, n-chunk of 512 --------
__global__ __launch_bounds__(256) void kv_part_kernel(
    const float* __restrict__ k_img, const float* __restrict__ v_img,
    float* __restrict__ kvp) {
    __shared__ float ks[16 * 132], vs[16 * 132];
    int bc = blockIdx.x;
    int bh = bc >> 3, chunk = bc & 7;
    int b = bh >> 3, h = bh & 7;
    int tid = threadIdx.x;
    int ck = tid >> 4, cv = tid & 15;
    float acc = 0.f;
    const float* kp = k_img + (size_t)(b * 128 + h * 16) * 4096;
    const float* vp = v_img + (size_t)(b * 128 + h * 16) * 4096;
    int nb0 = chunk * 512;
    for (int nb = nb0; nb < nb0 + 512; nb += 128) {
        for (int idx = tid; idx < 2048; idx += 256) {
            int r = idx >> 7, col = idx & 127;
            ks[r * 132 + col] = kp[(size_t)r * 4096 + nb + col];
            vs[r * 132 + col] = vp[(size_t)r * 4096 + nb + col];
        }
        __syncthreads();
        for (int kk = 0; kk < 128; ++kk)
            acc += ks[ck * 132 + kk] * vs[cv * 132 + kk];
        __syncthreads();
    }
    kvp[(size_t)(chunk * 64 + bh) * 256 + ck * 16 + cv] = acc;
}

// ---------------- fa (with inline kvp reduce) ------------------------------
__global__ __launch_bounds__(256) void fa_kernel(
    const float* __restrict__ q_img, const float* __restrict__ kvp,
    float* __restrict__ fa_img) {
    __shared__ float kvs[256];
    int bid = blockIdx.x;
    int bh = bid >> 4, chunk = bid & 15;
    int b = bh >> 3, h = bh & 7;
    int tid = threadIdx.x;
    {
        float s = 0.f;
        #pragma unroll
        for (int c = 0; c < 8; ++c) s += kvp[(size_t)c * 16384 + bh * 256 + tid];
        kvs[tid] = s;
    }
    __syncthreads();
    int n = chunk * 256 + tid;
    const float* qp = q_img + (size_t)(b * 128 + h * 16) * 4096 + n;
    float qv[16];
    #pragma unroll
    for (int ck = 0; ck < 16; ++ck) qv[ck] = qp[(size_t)ck * 4096];
    float* fp = fa_img + (size_t)(b * 128 + h * 16) * 4096 + n;
    #pragma unroll
    for (int cv = 0; cv < 16; ++cv) {
        float s = 0.f;
        #pragma unroll
        for (int ck = 0; ck < 16; ++ck) s += qv[ck] * kvs[ck * 16 + cv];
        fp[(size_t)cv * 4096] = s;
    }
}

// ---------------- conv helper: 4 outputs, compile-time KC (rule #20) -------
template<int KC>
__device__ __forceinline__ void conv4(const float* __restrict__ s,
                                      const float* __restrict__ wsm,
                                      int y, int xx0, float* a4) {
    const int OFF = KC / 2;
    #pragma unroll
    for (int dy = 0; dy < KC; ++dy) {
        int sy = y + dy - OFF;
        if (sy < 0 || sy >= 64) continue;
        const float* r = s + sy * 72;
        float u[12];
        *(f32x4*)&u[0] = *(const f32x4*)&r[xx0];
        *(f32x4*)&u[4] = *(const f32x4*)&r[xx0 + 4];
        *(f32x4*)&u[8] = *(const f32x4*)&r[xx0 + 8];
        #pragma unroll
        for (int dx = 0; dx < KC; ++dx) {
            float w = wsm[dy * KC + dx];
            const int base = dx - OFF + 4;
            a4[0] += u[base + 0] * w;
            a4[1] += u[base + 1] * w;
            a4[2] += u[base + 2] * w;
            a4[3] += u[base + 3] * w;
        }
    }
}

// ---------------- crpe conv + combine (fa precomputed) ---------------------
__global__ __launch_bounds__(256) void att_kernel(
    const float* __restrict__ q_img, const float* __restrict__ v_img,
    const float* __restrict__ fa_img, const float* __restrict__ da,
    const float* __restrict__ w3, const float* __restrict__ b3,
    const float* __restrict__ w5, const float* __restrict__ b5,
    const float* __restrict__ w7, const float* __restrict__ b7,
    float* __restrict__ att) {
    __shared__ float s[64 * 72];
    __shared__ float wsm[49];
    int o = ((blockIdx.x & 7) << 7) | (blockIdx.x >> 3);
    int b = o >> 7, c = o & 127;
    int tid = threadIdx.x;
    const float* vp = v_img + (size_t)(b * 128 + c) * 4096;
    for (int idx = tid; idx < 4096; idx += 256) {
        int row = idx >> 6, xx = idx & 63;
        s[row * 72 + xx + 4] = vp[idx];
    }
    for (int idx = tid; idx < 512; idx += 256) {
        int row = idx >> 3, j = idx & 7;
        s[row * 72 + (j < 4 ? j : 64 + j)] = 0.f;
    }
    int kc; const float* wp; float bias;
    if (c < 32)      { kc = 3; wp = w3 + c * 9;         bias = b3[c]; }
    else if (c < 80) { kc = 5; wp = w5 + (c - 32) * 25; bias = b5[c - 32]; }
    else             { kc = 7; wp = w7 + (c - 80) * 49; bias = b7[c - 80]; }
    if (tid < kc * kc) wsm[tid] = wp[tid];
    float dac = da[b * 128 + c];
    size_t rowbase = (size_t)(b * 128 + c) * 4096;
    __syncthreads();
    for (int it = 0; it < 4; ++it) {
        int task = tid + it * 256;
        int y = task >> 4, xx0 = (task & 15) * 4;
        float a4[4] = {bias, bias, bias, bias};
        if (kc == 3)      conv4<3>(s, wsm, y, xx0, a4);
        else if (kc == 5) conv4<5>(s, wsm, y, xx0, a4);
        else              conv4<7>(s, wsm, y, xx0, a4);
        size_t base = rowbase + y * 64 + xx0;
        f32x4 fav = *(const f32x4*)&fa_img[base];
        f32x4 qv  = *(const f32x4*)&q_img[base];
        f32x4 cv4 = {a4[0], a4[1], a4[2], a4[3]};
        f32x4 r = (fav * 0.25f + qv * cv4) * dac;
        *(f32x4*)&att[base] = r;
    }
}

// ---------------- MFMA proj + residual: A = att (image layout) -------------
__global__ __launch_bounds__(256, 2) void proj_mfma_kernel(
    const float* __restrict__ att, const short* __restrict__ wp,
    const float* __restrict__ bias, const float* __restrict__ xres,
    float* __restrict__ out) {
    __shared__ float As[128 * 33];
    int tb = blockIdx.x * 32;
    int tid = threadIdx.x;
    int lane = tid & 63, wv = tid >> 6;
    int lhi = lane >> 4, llo = lane & 15;
    int b = tb >> 12, n0 = tb & 4095;

    for (int idx = tid; idx < 4096; idx += 256) {
        int c = idx >> 5, t = idx & 31;
        As[c * 33 + t] = att[(size_t)(b * 128 + c) * 4096 + n0 + t];
    }
    __syncthreads();

    bf16x8 afr[2][4];
    #pragma unroll
    for (int tt = 0; tt < 2; ++tt) {
        #pragma unroll
        for (int kk = 0; kk < 4; ++kk) {
            int c0 = kk * 32 + lhi * 8;
            int t = tt * 16 + llo;
            bf16x8 v;
            #pragma unroll
            for (int j = 0; j < 8; ++j) v[j] = f2bf(As[(c0 + j) * 33 + t]);
            afr[tt][kk] = v;
        }
    }

    f32x4 acc[2][2];
    f32x4 zr = {0.f, 0.f, 0.f, 0.f};
    #pragma unroll
    for (int i = 0; i < 2; ++i) { acc[i][0] = zr; acc[i][1] = zr; }

    #pragma unroll
    for (int i = 0; i < 2; ++i) {
        int nb = wv * 2 + i;
        #pragma unroll
        for (int kk = 0; kk < 4; ++kk) {
            bf16x8 wf = *(const bf16x8*)&wp[((size_t)(nb * 4 + kk) * 64 + lane) * 8];
            acc[i][0] = __builtin_amdgcn_mfma_f32_16x16x32_bf16(wf, afr[0][kk], acc[i][0], 0, 0, 0);
            acc[i][1] = __builtin_amdgcn_mfma_f32_16x16x32_bf16(wf, afr[1][kk], acc[i][1], 0, 0, 0);
        }
    }

    #pragma unroll
    for (int i = 0; i < 2; ++i) {
        int j0 = (wv * 2 + i) * 16;
        f32x4 bv = *(const f32x4*)(bias + j0 + lhi * 4);
        #pragma unroll
        for (int tt = 0; tt < 2; ++tt) {
            size_t o = (size_t)(tb + tt * 16 + llo) * 128 + j0 + lhi * 4;
            f32x4 xr = *(const f32x4*)(xres + o);
            *(f32x4*)(out + o) = xr + acc[i][tt] + bv;
        }
    }
}

// ---------------- fused MFMA MLP (LN2 fused): 512 thr, 8 waves -------------
// Round-10 structure (proven 60us, VGPR 52, no spill): wave wv -> tt = wv&1,
// hidden group g = wv>>1 (hn = g*16+nl). GEMM2: wave wv -> cout block wv.
// + fast gelu. NO aggressive launch_bounds min-waves (round-12 lesson:
// capping VGPR below ~100 live regs -> scratch spill, 263MB traffic).
// nl loop fully unrolled (rule #20).
__global__ __launch_bounds__(512, 4) void mlp_mfma_kernel(
    const short* __restrict__ w1p, const float* __restrict__ b1p,
    const short* __restrict__ w2p, const float* __restrict__ b2,
    float* io) {
    __shared__ short hs[32768];
    int tb = blockIdx.x * 32;
    int tid = threadIdx.x;
    int lane = tid & 63, wv = tid >> 6;
    int tt = wv & 1, g = wv >> 1;
    int lhi = lane >> 4, llo = lane & 15;

    bf16x8 afr[4];
    {
        f32x4 v0[4], v1[4];
        float sum = 0.f;
        #pragma unroll
        for (int kk = 0; kk < 4; ++kk) {
            const float* p = io + (size_t)(tb + tt * 16 + llo) * 128 + kk * 32 + lhi * 8;
            v0[kk] = *(const f32x4*)p;
            v1[kk] = *(const f32x4*)(p + 4);
            sum += v0[kk].x + v0[kk].y + v0[kk].z + v0[kk].w
                 + v1[kk].x + v1[kk].y + v1[kk].z + v1[kk].w;
        }
        sum += __shfl_xor(sum, 16, 64);
        sum += __shfl_xor(sum, 32, 64);
        float mean = sum * (1.f / 128.f);
        float vs = 0.f;
        #pragma unroll
        for (int kk = 0; kk < 4; ++kk) {
            f32x4 a = v0[kk], c = v1[kk];
            float d0 = a.x - mean, d1 = a.y - mean, d2 = a.z - mean, d3 = a.w - mean;
            float d4 = c.x - mean, d5 = c.y - mean, d6 = c.z - mean, d7 = c.w - mean;
            vs += d0*d0 + d1*d1 + d2*d2 + d3*d3 + d4*d4 + d5*d5 + d6*d6 + d7*d7;
        }
        vs += __shfl_xor(vs, 16, 64);
        vs += __shfl_xor(vs, 32, 64);
        float rs = rsqrtf(vs * (1.f / 128.f) + EPS_LN);
        #pragma unroll
        for (int kk = 0; kk < 4; ++kk) {
            bf16x8 o;
            o[0] = f2bf((v0[kk].x - mean) * rs);
            o[1] = f2bf((v0[kk].y - mean) * rs);
            o[2] = f2bf((v0[kk].z - mean) * rs);
            o[3] = f2bf((v0[kk].w - mean) * rs);
            o[4] = f2bf((v1[kk].x - mean) * rs);
            o[5] = f2bf((v1[kk].y - mean) * rs);
            o[6] = f2bf((v1[kk].z - mean) * rs);
            o[7] = f2bf((v1[kk].w - mean) * rs);
            afr[kk] = o;
        }
    }

    f32x4 acc[16];
    f32x4 zr = {0.f, 0.f, 0.f, 0.f};
    #pragma unroll
    for (int nl = 0; nl < 16; ++nl) acc[nl] = zr;

    const short* wbase = w1p + (size_t)(g * 16) * 4 * 64 * 8;
    #pragma unroll
    for (int nl = 0; nl < 16; ++nl) {
        #pragma unroll
        for (int kk = 0; kk < 4; ++kk) {
            bf16x8 bf = *(const bf16x8*)(wbase + ((size_t)(nl * 4 + kk) * 64 + lane) * 8);
            acc[nl] = __builtin_amdgcn_mfma_f32_16x16x32_bf16(bf, afr[kk], acc[nl], 0, 0, 0);
        }
    }

    #pragma unroll
    for (int nl = 0; nl < 16; ++nl) {
        int hn = g * 16 + nl;
        int hc0 = hn * 16 + lhi * 4;
        f32x4 bv = *(const f32x4*)(b1p + hc0);
        int kk2 = hn >> 1;
        int lp = llo + 16 * ((hn & 1) * 2 + (lhi >> 1));
        f32x4 a = acc[nl] + bv;
        uint2 wv2;
        wv2.x = pack2bf(gelu_f(a.x), gelu_f(a.y));
        wv2.y = pack2bf(gelu_f(a.z), gelu_f(a.w));
        *(uint2*)((char*)hs + ((size_t)(tt * 32 + kk2) * 64 + lp) * 16 + (lhi & 1) * 8) = wv2;
    }
    __syncthreads();

    f32x4 acc2[2];
    acc2[0] = zr; acc2[1] = zr;

    const short* w2base = w2p + (size_t)wv * 32 * 64 * 8;
    #pragma unroll 4
    for (int kk2 = 0; kk2 < 32; ++kk2) {
        bf16x8 h0 = *(const bf16x8*)&hs[((size_t)(0 * 32 + kk2) * 64 + lane) * 8];
        bf16x8 h1 = *(const bf16x8*)&hs[((size_t)(1 * 32 + kk2) * 64 + lane) * 8];
        bf16x8 w0 = *(const bf16x8*)(w2base + ((size_t)kk2 * 64 + lane) * 8);
        acc2[0] = __builtin_amdgcn_mfma_f32_16x16x32_bf16(w0, h0, acc2[0], 0, 0, 0);
        acc2[1] = __builtin_amdgcn_mfma_f32_16x16x32_bf16(w0, h1, acc2[1], 0, 0, 0);
    }

    int c0 = wv * 16 + lhi * 4;
    f32x4 bv = *(const f32x4*)(b2 + c0);
    #pragma unroll
    for (int tt2 = 0; tt2 < 2; ++tt2) {
        float* op = io + (size_t)(tb + tt2 * 16 + llo) * 128 + c0;
        f32x4 r = *(f32x4*)op;
        r = r + acc2[tt2] + bv;
        *(f32x4*)op = r;
    }
}

extern "C" void kernel_launch(void* const* d_in, const int* in_sizes, int n_in,
                              void* d_out, int out_size, void* d_ws, size_t ws_size,
                              hipStream_t stream) {
    const float* img   = (const float*)d_in[0];
    const float* dl    = (const float*)d_in[1];
    const float* pe_dw = (const float*)d_in[2];
    const float* pe_pw = (const float*)d_in[3];
    const float* bn_g  = (const float*)d_in[4];
    const float* bn_b  = (const float*)d_in[5];
    const float* bn_m  = (const float*)d_in[6];
    const float* bn_v  = (const float*)d_in[7];
    const float* cpe_w = (const float*)d_in[8];
    const float* cpe_b = (const float*)d_in[9];
    const float* n1_g  = (const float*)d_in[10];
    const float* n1_b  = (const float*)d_in[11];
    const float* qkv_w = (const float*)d_in[12];
    const float* qkv_b = (const float*)d_in[13];
    const float* w3    = (const float*)d_in[14];
    const float* b3    = (const float*)d_in[15];
    const float* w5    = (const float*)d_in[16];
    const float* b5    = (const float*)d_in[17];
    const float* w7    = (const float*)d_in[18];
    const float* b7    = (const float*)d_in[19];
    const float* dw1   = (const float*)d_in[20];
    const float* db1   = (const float*)d_in[21];
    const float* dw2   = (const float*)d_in[22];
    const float* db2   = (const float*)d_in[23];
    const float* pw    = (const float*)d_in[24];
    const float* pb    = (const float*)d_in[25];
    const float* n2_g  = (const float*)d_in[26];
    const float* n2_b  = (const float*)d_in[27];
    const float* f1w   = (const float*)d_in[28];
    const float* f1b   = (const float*)d_in[29];
    const float* f2w   = (const float*)d_in[30];
    const float* f2b   = (const float*)d_in[31];
    const int*   dptr  = (const int*)d_in[32];
    float* out = (float*)d_out;

    char* ws = (char*)d_ws;
    const size_t SZ = (size_t)8 * 128 * 4096 * 4;   // 16,777,216 bytes
    float* t1    = (float*)(ws);            // pe out; dead after cpe -> fa_img
    float* x     = (float*)(ws + SZ);       // residual stream after cpe
    float* q_img = (float*)(ws + 2 * SZ);
    float* k_img = (float*)(ws + 3 * SZ);   // att output after kv
    float* v_img = (float*)(ws + 4 * SZ);
    float* da    = (float*)(ws + 5 * SZ + 0x10000);
    short* qkvp  = (short*)(ws + 5 * SZ + 0x20000);
    short* pwp   = (short*)(ws + 5 * SZ + 0x40000);
    float* qbp   = (float*)(ws + 5 * SZ + 0x48000);
    float* f1bp  = (float*)(ws + 5 * SZ + 0x4A000);
    float* kvp   = (float*)(ws + 5 * SZ + 0x50000);
    short* w1p   = (short*)(ws + 5 * SZ + 0xD0000);
    short* w2p   = (short*)(ws + 5 * SZ + 0x110000);
    float* fa_img = t1;

    prep_kernel<<<167, 256, 0, stream>>>(qkv_w, n1_g, n1_b, qkv_b, pw, f1w,
                                         n2_g, n2_b, f1b, f2w, dl, dw1, db1,
                                         dw2, db2, dptr, qkvp, pwp, w1p, w2p,
                                         qbp, f1bp, da);
    pe_kernel<<<512, 256, 0, stream>>>(img, pe_dw, pe_pw, bn_g, bn_b, bn_m, bn_v, dptr, t1);
    cpe_kernel<<<2048, 256, 0, stream>>>(t1, cpe_w, cpe_b, x);
    qkv_mfma_kernel<<<1024, 512, 0, stream>>>(x, qkvp, qbp, q_img, k_img, v_img);
    softmax_kernel<<<1024, 256, 0, stream>>>(k_img);
    kv_part_kernel<<<512, 256, 0, stream>>>(k_img, v_img, kvp);
    fa_kernel<<<1024, 256, 0, stream>>>(q_img, kvp, fa_img);
    att_kernel<<<1024, 256, 0, stream>>>(q_img, v_img, fa_img, da, w3, b3, w5, b5, w7, b7, k_img);
    proj_mfma_kernel<<<1024, 256, 0, stream>>>(k_img, pwp, pb, x, out);
    mlp_mfma_kernel<<<1024, 512, 0, stream>>>(w1p, f1bp, w2p, f2b, out);
}